// Round 1
// baseline (1095.338 us; speedup 1.0000x reference)
//
#include <hip/hip_runtime.h>

#define N_NODES 100000
#define N_EDGES 1600000
#define SCAN_BLOCKS ((N_NODES + 255) / 256)   // 391

// ---------------- CSR build ----------------

__global__ void count_deg(const int* __restrict__ dst, int* __restrict__ deg, int E) {
    int i = blockIdx.x * blockDim.x + threadIdx.x;
    if (i < E) atomicAdd(&deg[dst[i]], 1);
}

__global__ void scan_partial(const int* __restrict__ deg, int* __restrict__ partial, int n) {
    __shared__ int s[256];
    int i = blockIdx.x * 256 + threadIdx.x;
    s[threadIdx.x] = (i < n) ? deg[i] : 0;
    __syncthreads();
    for (int o = 128; o > 0; o >>= 1) {
        if (threadIdx.x < o) s[threadIdx.x] += s[threadIdx.x + o];
        __syncthreads();
    }
    if (threadIdx.x == 0) partial[blockIdx.x] = s[0];
}

// single block, exclusive scan of partial[0..nb), nb <= 512
__global__ void scan_top(int* __restrict__ partial, int nb) {
    __shared__ int s[512];
    int t = threadIdx.x;
    s[t] = (t < nb) ? partial[t] : 0;
    __syncthreads();
    for (int o = 1; o < 512; o <<= 1) {
        int v = (t >= o) ? s[t - o] : 0;
        __syncthreads();
        s[t] += v;
        __syncthreads();
    }
    if (t < nb) partial[t] = (t == 0) ? 0 : s[t - 1];
}

__global__ void scan_final(const int* __restrict__ deg, const int* __restrict__ partial,
                           int* __restrict__ row_ptr, int* __restrict__ cursor, int n) {
    __shared__ int s[256];
    int i = blockIdx.x * 256 + threadIdx.x;
    int t = threadIdx.x;
    int v = (i < n) ? deg[i] : 0;
    s[t] = v;
    __syncthreads();
    for (int o = 1; o < 256; o <<= 1) {
        int pv = (t >= o) ? s[t - o] : 0;
        __syncthreads();
        s[t] += pv;
        __syncthreads();
    }
    int base = partial[blockIdx.x];
    if (i < n) {
        int excl = base + s[t] - v;   // exclusive scan value
        row_ptr[i] = excl;
        cursor[i]  = excl;
    }
    if (i == n - 1) row_ptr[n] = base + s[t];  // == E
}

__global__ void fill_csr(const int* __restrict__ src, const int* __restrict__ dst,
                         int* __restrict__ cursor, int* __restrict__ col, int E) {
    int i = blockIdx.x * blockDim.x + threadIdx.x;
    if (i < E) {
        int d = dst[i];
        int pos = atomicAdd(&cursor[d], 1);
        col[pos] = src[i];
    }
}

// ---------------- GEMM: H[r][c] = sum_k X[r][k] * W[k][c] ----------------
// thread = one row; blockIdx.y = uniform 32-col chunk -> W reads are wave-uniform
// (compiler emits s_load; v_fmac takes the SGPR operand directly). No LDS.
template <int DOUT>
__global__ void __launch_bounds__(256) gemm_rows(const float* __restrict__ X,
                                                 const float* __restrict__ W,
                                                 float* __restrict__ H, int n) {
    const int row = blockIdx.x * 256 + threadIdx.x;
    const int c0  = blockIdx.y * 32;
    if (row >= n) return;
    float acc[32];
#pragma unroll
    for (int i = 0; i < 32; i++) acc[i] = 0.f;
    const float* xr = X + (size_t)row * 128;
    for (int k = 0; k < 128; k += 4) {
        float4 xv = *(const float4*)(xr + k);
        const float* w0 = W + (size_t)k * DOUT + c0;
        const float* w1 = w0 + DOUT;
        const float* w2 = w1 + DOUT;
        const float* w3 = w2 + DOUT;
#pragma unroll
        for (int i = 0; i < 32; i++) acc[i] += xv.x * w0[i];
#pragma unroll
        for (int i = 0; i < 32; i++) acc[i] += xv.y * w1[i];
#pragma unroll
        for (int i = 0; i < 32; i++) acc[i] += xv.z * w2[i];
#pragma unroll
        for (int i = 0; i < 32; i++) acc[i] += xv.w * w3[i];
    }
    float* hr = H + (size_t)row * DOUT + c0;
#pragma unroll
    for (int i = 0; i < 32; i++) hr[i] = acc[i];
}

// ---------------- Aggregation: OUT[v] = sum over in-edges of H[src] ----------------
// one wave (64 lanes) per node; D=128: lane owns a float2; D=64: lane owns a float.
// Edge loop unrolled x4 for memory-level parallelism (idx->feature is a dependent chain).
template <int D>
__global__ void __launch_bounds__(256) aggregate(const float* __restrict__ H,
                                                 const int* __restrict__ row_ptr,
                                                 const int* __restrict__ col,
                                                 float* __restrict__ OUT, int n) {
    int gid  = blockIdx.x * blockDim.x + threadIdx.x;
    int node = gid >> 6;
    int lane = gid & 63;
    if (node >= n) return;
    int e   = row_ptr[node];
    int end = row_ptr[node + 1];

    if (D == 128) {
        const float2* H2 = (const float2*)H;
        float2 acc = make_float2(0.f, 0.f);
        for (; e + 4 <= end; e += 4) {
            int s0 = col[e], s1 = col[e + 1], s2 = col[e + 2], s3 = col[e + 3];
            float2 v0 = H2[(size_t)s0 * 64 + lane];
            float2 v1 = H2[(size_t)s1 * 64 + lane];
            float2 v2 = H2[(size_t)s2 * 64 + lane];
            float2 v3 = H2[(size_t)s3 * 64 + lane];
            acc.x += (v0.x + v1.x) + (v2.x + v3.x);
            acc.y += (v0.y + v1.y) + (v2.y + v3.y);
        }
        for (; e < end; e++) {
            int s = col[e];
            float2 v = H2[(size_t)s * 64 + lane];
            acc.x += v.x;
            acc.y += v.y;
        }
        ((float2*)OUT)[(size_t)node * 64 + lane] = acc;
    } else {  // D == 64
        float acc = 0.f;
        for (; e + 4 <= end; e += 4) {
            int s0 = col[e], s1 = col[e + 1], s2 = col[e + 2], s3 = col[e + 3];
            float v0 = H[(size_t)s0 * 64 + lane];
            float v1 = H[(size_t)s1 * 64 + lane];
            float v2 = H[(size_t)s2 * 64 + lane];
            float v3 = H[(size_t)s3 * 64 + lane];
            acc += (v0 + v1) + (v2 + v3);
        }
        for (; e < end; e++) acc += H[(size_t)col[e] * 64 + lane];
        OUT[(size_t)node * 64 + lane] = acc;
    }
}

// ---------------- launch ----------------

static inline size_t align_up(size_t x, size_t a) { return (x + a - 1) & ~(a - 1); }

extern "C" void kernel_launch(void* const* d_in, const int* in_sizes, int n_in,
                              void* d_out, int out_size, void* d_ws, size_t ws_size,
                              hipStream_t stream) {
    const float* x  = (const float*)d_in[0];
    const int*   ei = (const int*)d_in[1];   // [2, E] int
    const float* W1 = (const float*)d_in[2];
    const float* W2 = (const float*)d_in[3];
    const float* W3 = (const float*)d_in[4];
    float* out = (float*)d_out;

    const int N = N_NODES;
    const int E = N_EDGES;
    const int* src = ei;
    const int* dst = ei + E;

    // workspace carve-up
    char* p = (char*)d_ws;
    int* deg     = (int*)p;  p += align_up((size_t)N * 4, 256);
    int* row_ptr = (int*)p;  p += align_up((size_t)(N + 1) * 4, 256);
    int* cursor  = (int*)p;  p += align_up((size_t)N * 4, 256);
    int* col     = (int*)p;  p += align_up((size_t)E * 4, 256);
    int* partial = (int*)p;  p += align_up((size_t)1024 * 4, 256);
    float* h_buf = (float*)p; p += align_up((size_t)N * 128 * 4, 256);
    float* a_buf = (float*)p; p += align_up((size_t)N * 128 * 4, 256);

    // ---- CSR build (reused by all 3 layers) ----
    hipMemsetAsync(deg, 0, (size_t)N * 4, stream);
    count_deg<<<(E + 255) / 256, 256, 0, stream>>>(dst, deg, E);
    scan_partial<<<SCAN_BLOCKS, 256, 0, stream>>>(deg, partial, N);
    scan_top<<<1, 512, 0, stream>>>(partial, SCAN_BLOCKS);
    scan_final<<<SCAN_BLOCKS, 256, 0, stream>>>(deg, partial, row_ptr, cursor, N);
    fill_csr<<<(E + 255) / 256, 256, 0, stream>>>(src, dst, cursor, col, E);

    const int gemm_bx = (N + 255) / 256;
    const int agg_blocks = (N * 64 + 255) / 256;

    // layer 1: h1 = x@W1 ; a1 = A@h1
    gemm_rows<128><<<dim3(gemm_bx, 4), 256, 0, stream>>>(x, W1, h_buf, N);
    aggregate<128><<<agg_blocks, 256, 0, stream>>>(h_buf, row_ptr, col, a_buf, N);
    // layer 2
    gemm_rows<128><<<dim3(gemm_bx, 4), 256, 0, stream>>>(a_buf, W2, h_buf, N);
    aggregate<128><<<agg_blocks, 256, 0, stream>>>(h_buf, row_ptr, col, a_buf, N);
    // layer 3 (64-wide out): transform first so edges move only 64 floats
    gemm_rows<64><<<dim3(gemm_bx, 2), 256, 0, stream>>>(a_buf, W3, h_buf, N);
    aggregate<64><<<agg_blocks, 256, 0, stream>>>(h_buf, row_ptr, col, out, N);
}